// Round 1
// baseline (888.251 us; speedup 1.0000x reference)
//
#include <hip/hip_runtime.h>

// Problem constants
#define HDIM 256
#define WDIM 256
#define DDIM 64
#define HWSZ (HDIM*WDIM)          // 65536
#define NPIX 524288               // 8 * 65536

// Tiling: 32 wide x 16 tall, 256 threads, each thread owns 2 vertically
// adjacent pixels (rows 2*ry and 2*ry+1). Halo = +3 each side.
#define TW 32
#define TH 16
#define HW_T 38                   // TW+6
#define HH_T 22                   // TH+6
#define NPX 836                   // HW_T*HH_T halo pixels
#define DC 8                      // d-chunk size
#define NCH 8                     // 64/DC
#define PSTR 12                   // padded floats per pixel (48B stride: 16B-aligned,
                                  // 12-bank stride -> conflict-free for b128)

// d_out layout (floats), reference return order:
// dy, dx, conf_local, conf_global, local_weight, logits
#define OFF_DY   0
#define OFF_DX   524288
#define OFF_CONF 1048576
#define OFF_CG   1572864
#define OFF_LW   1572872
#define OFF_LG   2097160

// workspace layout (floats)
#define WS_GACC 0                 // 8*49 logit sums
#define WS_DYG  392
#define WS_DXG  400

__global__ void zero_ws_k(float* __restrict__ ws) {
    const int i = threadIdx.x;
    if (i < 408) ws[i] = 0.f;
}

__global__ void __launch_bounds__(256, 2)
corr_main_k(const float* __restrict__ rub, const float* __restrict__ vis,
            const float* __restrict__ ltemp, float* __restrict__ out,
            float* __restrict__ ws)
{
    __shared__ __align__(16) float vis_s[NPX * PSTR];   // 40128 B
    __shared__ float invv_s[NPX];                        // 3344 B

    const int tid = threadIdx.x;
    const int tx  = tid & 31;
    const int ry  = tid >> 5;                 // 0..7
    const int w0  = blockIdx.x * TW;
    const int h0  = blockIdx.y * TH;
    const int b   = blockIdx.z;
    const int ibase = b * (DDIM * HWSZ);

    // Staging assignment: thread covers halo pixels tid, tid+256, tid+512, tid+768.
    // Fixed across all d-chunks -> per-thread sumsq accumulation gives vis norms free.
    int goff[4], lofs[4], pxl[4];
    bool val[4];
    float sq[4] = {0.f, 0.f, 0.f, 0.f};
#pragma unroll
    for (int j = 0; j < 4; ++j) {
        const int px = tid + 256 * j;
        pxl[j] = px;
        val[j] = (px < NPX);
        const int hr = px / HW_T;
        const int wc = px - hr * HW_T;
        const int gh = min(HDIM - 1, max(0, h0 - 3 + hr));   // edge-replicate pad
        const int gw = min(WDIM - 1, max(0, w0 - 3 + wc));
        goff[j] = gh * WDIM + gw;
        lofs[j] = px * PSTR;
    }

    const int hp0 = h0 + 2 * ry;              // own pixel rows: hp0, hp0+1
    const int wp  = w0 + tx;

    float acc0[49], acc1[49];
#pragma unroll
    for (int k = 0; k < 49; ++k) { acc0[k] = 0.f; acc1[k] = 0.f; }
    float sr0 = 0.f, sr1 = 0.f;

    const float* vb = &vis_s[(2 * ry * HW_T + tx) * PSTR];

#pragma unroll 1
    for (int c = 0; c < NCH; ++c) {
        const int d0 = c * DC;
        float r0[DC], r1[DC];
        // Stage raw vis chunk -> LDS (+sumsq), raw rubin chunk -> regs (+sumsq)
#pragma unroll
        for (int d = 0; d < DC; ++d) {
            const int gof = ibase + (d0 + d) * HWSZ;
#pragma unroll
            for (int j = 0; j < 4; ++j) {
                if (val[j]) {
                    const float v = vis[gof + goff[j]];
                    vis_s[lofs[j] + d] = v;
                    sq[j] += v * v;
                }
            }
            r0[d] = rub[gof + hp0 * WDIM + wp];
            r1[d] = rub[gof + (hp0 + 1) * WDIM + wp];
            sr0 += r0[d] * r0[d];
            sr1 += r1[d] * r1[d];
        }
        __syncthreads();
        // Correlation: 8 halo rows x 7 cols, each b128 (4 d) serves both pixels.
        // All LDS offsets compile-time immediates off vb.
#pragma unroll
        for (int g = 0; g < 2; ++g) {
            const float a00 = r0[4*g+0], a01 = r0[4*g+1], a02 = r0[4*g+2], a03 = r0[4*g+3];
            const float a10 = r1[4*g+0], a11 = r1[4*g+1], a12 = r1[4*g+2], a13 = r1[4*g+3];
#pragma unroll
            for (int rr2 = 0; rr2 < 8; ++rr2) {
#pragma unroll
                for (int dxi = 0; dxi < 7; ++dxi) {
                    const float4 v = *reinterpret_cast<const float4*>(
                        vb + rr2 * (HW_T * PSTR) + dxi * PSTR + 4 * g);
                    if (rr2 < 7) {           // pixel 0: dy = rr2-3
                        float a = acc0[rr2 * 7 + dxi];
                        a = fmaf(a00, v.x, a); a = fmaf(a01, v.y, a);
                        a = fmaf(a02, v.z, a); a = fmaf(a03, v.w, a);
                        acc0[rr2 * 7 + dxi] = a;
                    }
                    if (rr2 > 0) {           // pixel 1: dy = rr2-4
                        float a = acc1[(rr2 - 1) * 7 + dxi];
                        a = fmaf(a10, v.x, a); a = fmaf(a11, v.y, a);
                        a = fmaf(a12, v.z, a); a = fmaf(a13, v.w, a);
                        acc1[(rr2 - 1) * 7 + dxi] = a;
                    }
                }
            }
        }
        __syncthreads();
    }

    // Publish vis inverse norms for the halo
#pragma unroll
    for (int j = 0; j < 4; ++j)
        if (val[j]) invv_s[pxl[j]] = 1.f / fmaxf(sqrtf(sq[j]), 1e-6f);
    __syncthreads();

    const float tau   = fmaxf(__expf(ltemp[0]), 1e-3f);
    const float itau  = 1.f / tau;
    const float invr0 = 1.f / fmaxf(sqrtf(sr0), 1e-6f);
    const float invr1 = 1.f / fmaxf(sqrtf(sr1), 1e-6f);
    const float uu    = 1.f / 49.f;
    const float i1mu  = 49.f / 48.f;

    // Epilogue per owned pixel: normalize logits, write them, softmax, local outputs.
    auto epilogue = [&](float (&accP)[49], const float invr, const int py) {
        const float cR = invr * 0.125f;          // scale = 1/sqrt(64)
        const int h = hp0 + py;
        const int lgbase = OFF_LG + b * 49 * HWSZ + h * WDIM + wp;
        float mlg = -1e30f;
#pragma unroll
        for (int dyi = 0; dyi < 7; ++dyi) {
            const int rowb = (2 * ry + py + dyi) * HW_T + tx;
#pragma unroll
            for (int dxi = 0; dxi < 7; ++dxi) {
                const int k = dyi * 7 + dxi;
                const float lg = accP[k] * cR * invv_s[rowb + dxi];
                out[lgbase + k * HWSZ] = lg;
                accP[k] = lg;                    // keep logit for global reduction
                mlg = fmaxf(mlg, lg);
            }
        }
        const float m = mlg * itau;              // itau > 0, monotone
        float S = 0.f, sdy = 0.f, sdx = 0.f;
#pragma unroll
        for (int dyi = 0; dyi < 7; ++dyi) {
#pragma unroll
            for (int dxi = 0; dxi < 7; ++dxi) {
                const int k = dyi * 7 + dxi;
                const float e = __expf(fmaf(accP[k], itau, -m));
                S += e;
                sdy += e * (float)(dyi - 3);
                sdx += e * (float)(dxi - 3);
            }
        }
        const float invS = 1.f / S;
        const float conf = invS;                 // max prob = exp(0)/S
        const float dyl = sdy * invS;
        const float dxl = sdx * invS;
        const float lw  = fminf(fmaxf((conf - uu) * i1mu, 0.f), 1.f);
        const int po = b * HWSZ + h * WDIM + wp;
        out[OFF_CONF + po] = conf;
        out[OFF_LW   + po] = lw;
        out[OFF_DY   + po] = dyl;   // local value; combine_k blends with global
        out[OFF_DX   + po] = dxl;
    };
    epilogue(acc0, invr0, 0);
    epilogue(acc1, invr1, 1);

    // Global-branch: sum logits over pixels per (b,k). Wave butterfly + 1 atomic/wave.
#pragma unroll
    for (int k = 0; k < 49; ++k) {
        float v = acc0[k] + acc1[k];
#pragma unroll
        for (int off = 32; off > 0; off >>= 1)
            v += __shfl_xor(v, off, 64);
        if ((tid & 63) == 0)
            atomicAdd(&ws[WS_GACC + b * 49 + k], v);
    }
}

__global__ void glob_branch_k(const float* __restrict__ ltemp,
                              float* __restrict__ out, float* __restrict__ ws)
{
    const int t = threadIdx.x;
    if (t >= 8) return;
    const float tau  = fmaxf(__expf(ltemp[0]), 1e-3f);
    const float itau = 1.f / tau;
    float tk[49];
    float m = -1e30f;
#pragma unroll
    for (int k = 0; k < 49; ++k) {
        const float mean = ws[WS_GACC + t * 49 + k] * (1.f / 65536.f);
        tk[k] = mean * itau;
        m = fmaxf(m, tk[k]);
    }
    float S = 0.f, sdy = 0.f, sdx = 0.f;
#pragma unroll
    for (int k = 0; k < 49; ++k) {
        const float e = __expf(tk[k] - m);
        S += e;
        sdy += e * (float)(k / 7 - 3);
        sdx += e * (float)(k % 7 - 3);
    }
    const float invS = 1.f / S;
    out[OFF_CG + t] = invS;                  // conf_global
    ws[WS_DYG + t] = sdy * invS;
    ws[WS_DXG + t] = sdx * invS;
}

__global__ void combine_k(float* __restrict__ out, const float* __restrict__ ws)
{
    const int gid = blockIdx.x * 256 + threadIdx.x;
    if (gid >= NPIX) return;
    const int b = gid >> 16;
    const float lw  = out[OFF_LW + gid];
    const float dyl = out[OFF_DY + gid];
    const float dxl = out[OFF_DX + gid];
    const float dyg = ws[WS_DYG + b];
    const float dxg = ws[WS_DXG + b];
    out[OFF_DY + gid] = lw * dyl + (1.f - lw) * dyg;
    out[OFF_DX + gid] = lw * dxl + (1.f - lw) * dxg;
}

extern "C" void kernel_launch(void* const* d_in, const int* in_sizes, int n_in,
                              void* d_out, int out_size, void* d_ws, size_t ws_size,
                              hipStream_t stream)
{
    const float* rub = (const float*)d_in[0];
    const float* vis = (const float*)d_in[1];
    const float* lt  = (const float*)d_in[2];
    float* out = (float*)d_out;
    float* ws  = (float*)d_ws;

    hipLaunchKernelGGL(zero_ws_k, dim3(1), dim3(512), 0, stream, ws);
    hipLaunchKernelGGL(corr_main_k, dim3(WDIM / TW, HDIM / TH, 8), dim3(256), 0, stream,
                       rub, vis, lt, out, ws);
    hipLaunchKernelGGL(glob_branch_k, dim3(1), dim3(64), 0, stream, lt, out, ws);
    hipLaunchKernelGGL(combine_k, dim3(NPIX / 256), dim3(256), 0, stream, out, ws);
}

// Round 2
// 396.476 us; speedup vs baseline: 2.2404x; 2.2404x over previous
//
#include <hip/hip_runtime.h>

// Problem constants
#define HDIM 256
#define WDIM 256
#define DDIM 64
#define HWSZ (HDIM*WDIM)          // 65536
#define NPIX 524288               // 8 * 65536

// Tiling: 32 wide x 16 tall, 512 threads, ONE pixel per thread (49 accs fit
// in VGPRs without spilling -- R1's 2px/98acc variant spilled at VGPR=112).
#define TW 32
#define TH 16
#define BT 512
#define HW_T 38                   // TW+6
#define HH_T 22                   // TH+6
#define NPX 836                   // HW_T*HH_T halo pixels
#define DC 8                      // d-chunk size
#define NCH 8                     // 64/DC
#define PSTR 12                   // padded floats per pixel: 48B stride, 16B-aligned,
                                  // lanes 0..7 tile all 32 banks exactly once for b128

// d_out layout (floats): dy, dx, conf_local, conf_global, local_weight, logits
#define OFF_DY   0
#define OFF_DX   524288
#define OFF_CONF 1048576
#define OFF_CG   1572864
#define OFF_LW   1572872
#define OFF_LG   2097160

// workspace layout (floats)
#define WS_GACC 0                 // 8*49 logit sums
#define WS_DYG  392
#define WS_DXG  400

__global__ void zero_ws_k(float* __restrict__ ws) {
    const int i = threadIdx.x;
    if (i < 408) ws[i] = 0.f;
}

__global__ void __launch_bounds__(BT, 4)   // cap 128 VGPR: guarantees no spill at ~100 use
corr_main_k(const float* __restrict__ rub, const float* __restrict__ vis,
            const float* __restrict__ ltemp, float* __restrict__ out,
            float* __restrict__ ws)
{
    __shared__ __align__(16) float vis_s[NPX * PSTR];   // 40128 B
    __shared__ float invv_s[NPX];                        // 3344 B
    __shared__ float gacc_s[49];

    const int tid = threadIdx.x;
    const int tx  = tid & 31;
    const int ty  = tid >> 5;                 // 0..15
    const int w0  = blockIdx.x * TW;
    const int h0  = blockIdx.y * TH;
    const int b   = blockIdx.z;
    const int ibase = b * (DDIM * HWSZ);

    if (tid < 49) gacc_s[tid] = 0.f;

    // Staging: thread covers halo px tid and tid+512 (clamped; the clamped
    // duplicate writes the same value to the same LDS slot -> benign).
    const bool val1 = (tid + BT) < NPX;
    const int px1c  = val1 ? (tid + BT) : (NPX - 1);
    auto halo_goff = [&](int px) -> int {
        const int hr = px / HW_T;
        const int wc = px - hr * HW_T;
        const int gh = min(HDIM - 1, max(0, h0 - 3 + hr));   // edge-replicate pad
        const int gw = min(WDIM - 1, max(0, w0 - 3 + wc));
        return gh * WDIM + gw;
    };
    const int goff0 = halo_goff(tid);
    const int goff1 = halo_goff(px1c);
    const int pown  = (h0 + ty) * WDIM + (w0 + tx);
    const int l0 = tid * PSTR;
    const int l1 = px1c * PSTR;

    float acc[49];
#pragma unroll
    for (int k = 0; k < 49; ++k) acc[k] = 0.f;
    float sq0 = 0.f, sq1 = 0.f, sr = 0.f;

    // Register prefetch pipeline: vv* stage chunk c's vis (written to LDS at
    // top of iter c), r cur/next double-buffer rubin.
    float vv0[DC], vv1[DC], rcur[DC], rnext[DC];
#pragma unroll
    for (int d = 0; d < DC; ++d) {
        const int gof = ibase + d * HWSZ;
        vv0[d]  = vis[gof + goff0];
        vv1[d]  = vis[gof + goff1];
        rcur[d] = rub[gof + pown];
    }

    const float* vb = &vis_s[(ty * HW_T + tx) * PSTR];

#pragma unroll 1
    for (int c = 0; c < NCH; ++c) {
        __syncthreads();                      // WAR: prior compute done
        *reinterpret_cast<float4*>(&vis_s[l0])     = make_float4(vv0[0], vv0[1], vv0[2], vv0[3]);
        *reinterpret_cast<float4*>(&vis_s[l0 + 4]) = make_float4(vv0[4], vv0[5], vv0[6], vv0[7]);
        *reinterpret_cast<float4*>(&vis_s[l1])     = make_float4(vv1[0], vv1[1], vv1[2], vv1[3]);
        *reinterpret_cast<float4*>(&vis_s[l1 + 4]) = make_float4(vv1[4], vv1[5], vv1[6], vv1[7]);
#pragma unroll
        for (int d = 0; d < DC; ++d) { sq0 += vv0[d] * vv0[d]; sq1 += vv1[d] * vv1[d]; }
        __syncthreads();                      // LDS visible

        if (c < NCH - 1) {                    // prefetch c+1 (in flight during compute)
#pragma unroll
            for (int d = 0; d < DC; ++d) {
                const int gof = ibase + ((c + 1) * DC + d) * HWSZ;
                vv0[d]  = vis[gof + goff0];
                vv1[d]  = vis[gof + goff1];
                rnext[d] = rub[gof + pown];
            }
        }

        // 98 ds_read_b128 + 392 FMA; all LDS offsets compile-time immediates
#pragma unroll
        for (int g = 0; g < 2; ++g) {
            const float a0 = rcur[4*g+0], a1 = rcur[4*g+1], a2 = rcur[4*g+2], a3 = rcur[4*g+3];
#pragma unroll
            for (int dyi = 0; dyi < 7; ++dyi) {
#pragma unroll
                for (int dxi = 0; dxi < 7; ++dxi) {
                    const float4 v = *reinterpret_cast<const float4*>(
                        vb + (dyi * HW_T + dxi) * PSTR + 4 * g);
                    float a = acc[dyi * 7 + dxi];
                    a = fmaf(a0, v.x, a); a = fmaf(a1, v.y, a);
                    a = fmaf(a2, v.z, a); a = fmaf(a3, v.w, a);
                    acc[dyi * 7 + dxi] = a;
                }
            }
        }
#pragma unroll
        for (int d = 0; d < DC; ++d) sr += rcur[d] * rcur[d];
#pragma unroll
        for (int d = 0; d < DC; ++d) rcur[d] = rnext[d];
    }

    // Publish vis inverse norms for the halo
    invv_s[tid] = 1.f / fmaxf(sqrtf(sq0), 1e-6f);
    if (val1) invv_s[tid + BT] = 1.f / fmaxf(sqrtf(sq1), 1e-6f);
    __syncthreads();

    const float tau  = fmaxf(__expf(ltemp[0]), 1e-3f);
    const float itau = 1.f / tau;
    const float invr = 1.f / fmaxf(sqrtf(sr), 1e-6f);
    const float cR   = invr * 0.125f;          // scale = 1/sqrt(64)
    const float uu   = 1.f / 49.f;
    const float i1mu = 49.f / 48.f;

    const int h = h0 + ty, w = w0 + tx;
    const int lgbase = OFF_LG + b * 49 * HWSZ + h * WDIM + w;
    float mlg = -1e30f;
#pragma unroll
    for (int dyi = 0; dyi < 7; ++dyi) {
        const int rowb = (ty + dyi) * HW_T + tx;
#pragma unroll
        for (int dxi = 0; dxi < 7; ++dxi) {
            const int k = dyi * 7 + dxi;
            const float lg = acc[k] * cR * invv_s[rowb + dxi];
            out[lgbase + k * HWSZ] = lg;
            acc[k] = lg;                       // keep logit for global reduction
            mlg = fmaxf(mlg, lg);
        }
    }
    const float m = mlg * itau;
    float S = 0.f, sdy = 0.f, sdx = 0.f;
#pragma unroll
    for (int dyi = 0; dyi < 7; ++dyi) {
#pragma unroll
        for (int dxi = 0; dxi < 7; ++dxi) {
            const float e = __expf(fmaf(acc[dyi * 7 + dxi], itau, -m));
            S += e;
            sdy += e * (float)(dyi - 3);
            sdx += e * (float)(dxi - 3);
        }
    }
    const float invS = 1.f / S;
    const float conf = invS;                   // max prob = exp(0)/S
    const float lw   = fminf(fmaxf((conf - uu) * i1mu, 0.f), 1.f);
    const int po = b * HWSZ + h * WDIM + w;
    out[OFF_CONF + po] = conf;
    out[OFF_LW   + po] = lw;
    out[OFF_DY   + po] = sdy * invS;           // local; combine_k blends with global
    out[OFF_DX   + po] = sdx * invS;

    // Global branch: wave butterfly -> LDS atomic -> one global atomic per block
#pragma unroll
    for (int k = 0; k < 49; ++k) {
        float v = acc[k];
#pragma unroll
        for (int off = 32; off > 0; off >>= 1)
            v += __shfl_xor(v, off, 64);
        if ((tid & 63) == 0) atomicAdd(&gacc_s[k], v);
    }
    __syncthreads();
    if (tid < 49) atomicAdd(&ws[WS_GACC + b * 49 + tid], gacc_s[tid]);
}

__global__ void glob_branch_k(const float* __restrict__ ltemp,
                              float* __restrict__ out, float* __restrict__ ws)
{
    const int t = threadIdx.x;
    if (t >= 8) return;
    const float tau  = fmaxf(__expf(ltemp[0]), 1e-3f);
    const float itau = 1.f / tau;
    float tk[49];
    float m = -1e30f;
#pragma unroll
    for (int k = 0; k < 49; ++k) {
        const float mean = ws[WS_GACC + t * 49 + k] * (1.f / 65536.f);
        tk[k] = mean * itau;
        m = fmaxf(m, tk[k]);
    }
    float S = 0.f, sdy = 0.f, sdx = 0.f;
#pragma unroll
    for (int k = 0; k < 49; ++k) {
        const float e = __expf(tk[k] - m);
        S += e;
        sdy += e * (float)(k / 7 - 3);
        sdx += e * (float)(k % 7 - 3);
    }
    const float invS = 1.f / S;
    out[OFF_CG + t] = invS;                  // conf_global
    ws[WS_DYG + t] = sdy * invS;
    ws[WS_DXG + t] = sdx * invS;
}

__global__ void combine_k(float* __restrict__ out, const float* __restrict__ ws)
{
    const int gid = blockIdx.x * 256 + threadIdx.x;
    if (gid >= NPIX) return;
    const int b = gid >> 16;
    const float lw  = out[OFF_LW + gid];
    const float dyl = out[OFF_DY + gid];
    const float dxl = out[OFF_DX + gid];
    out[OFF_DY + gid] = lw * dyl + (1.f - lw) * ws[WS_DYG + b];
    out[OFF_DX + gid] = lw * dxl + (1.f - lw) * ws[WS_DXG + b];
}

extern "C" void kernel_launch(void* const* d_in, const int* in_sizes, int n_in,
                              void* d_out, int out_size, void* d_ws, size_t ws_size,
                              hipStream_t stream)
{
    const float* rub = (const float*)d_in[0];
    const float* vis = (const float*)d_in[1];
    const float* lt  = (const float*)d_in[2];
    float* out = (float*)d_out;
    float* ws  = (float*)d_ws;

    hipLaunchKernelGGL(zero_ws_k, dim3(1), dim3(512), 0, stream, ws);
    hipLaunchKernelGGL(corr_main_k, dim3(WDIM / TW, HDIM / TH, 8), dim3(BT), 0, stream,
                       rub, vis, lt, out, ws);
    hipLaunchKernelGGL(glob_branch_k, dim3(1), dim3(64), 0, stream, lt, out, ws);
    hipLaunchKernelGGL(combine_k, dim3(NPIX / 256), dim3(256), 0, stream, out, ws);
}